// Round 2
// baseline (281.430 us; speedup 1.0000x reference)
//
#include <hip/hip_runtime.h>

// HexaToParallelogram: out[b,s,qi,ri] = (|q+r|<=18) ? hexa[b,s,idx(q,r)] : 0
// with q=qi-18, r=ri-18, idx from the sorted (q,r) enumeration (1027 pixels).
//
// Closed-form index (verified against the Python _build_lookup construction):
//   prefix(q<=0) = (55+q)(q+18)/2
//   prefix(q>=0) = 495 + 37q - q(q-1)/2
//   idx(q,r)     = prefix(q) + r - max(-18, -18-q)
//
// Structure: one block stages 4 input rows (the contiguous 4156-float span
// 4b*1039 .. 4b*1039+4156, which is float4-aligned and exactly covers the
// 4 rows incl. the 12-float tail gaps) into LDS with coalesced float4 loads,
// then emits 4 output rows (5476 floats = 1369 float4s, base 4b*1369 also
// 16B-aligned) via LDS gather + coalesced float4 stores.

#define IN_STRIDE   1039
#define OUT_ROW     1369        // 37*37
#define GDIM        37
#define ROWS_PB     4
#define LDS_FLOATS  (ROWS_PB * IN_STRIDE)     // 4156
#define LDS_VEC     (LDS_FLOATS / 4)          // 1039 float4s
#define OUT_VEC     ((ROWS_PB * OUT_ROW) / 4) // 1369 float4s
#define BLOCK       256

__global__ __launch_bounds__(BLOCK) void HexaToParallelogram_kernel(
        const float* __restrict__ in, float* __restrict__ out)
{
    __shared__ float lds[LDS_FLOATS];

    const unsigned b  = blockIdx.x;
    const size_t in_base  = (size_t)b * (ROWS_PB * IN_STRIDE);
    const size_t out_base = (size_t)b * (ROWS_PB * OUT_ROW);

    // Stage 4 input rows (with gaps) into LDS, fully coalesced float4.
    const float4* __restrict__ src = reinterpret_cast<const float4*>(in + in_base);
    float4* dstl = reinterpret_cast<float4*>(lds);
    for (unsigned i = threadIdx.x; i < LDS_VEC; i += BLOCK)
        dstl[i] = src[i];
    __syncthreads();

    // Emit 1369 float4s of output via LDS gather.
    float4* __restrict__ dst = reinterpret_cast<float4*>(out + out_base);
    for (unsigned f = threadIdx.x; f < OUT_VEC; f += BLOCK) {
        float v[4];
        const unsigned e = f * 4u;
#pragma unroll
        for (int k = 0; k < 4; ++k) {
            unsigned ek = e + (unsigned)k;        // 0..5475
            unsigned li = ek / OUT_ROW;           // local row 0..3
            unsigned j  = ek - li * OUT_ROW;      // 0..1368
            int qi = (int)(j / GDIM);
            int ri = (int)j - qi * GDIM;
            int q = qi - 18;
            int r = ri - 18;
            int s = q + r;
            float val = 0.0f;
            if (s >= -18 && s <= 18) {
                int idx;
                if (q <= 0) {
                    idx = ((55 + q) * (q + 18)) / 2 + r + 18 + q;
                } else {
                    idx = 495 + 37 * q - (q * (q - 1)) / 2 + r + 18;
                }
                val = lds[li * IN_STRIDE + idx];
            }
            v[k] = val;
        }
        float4 o;
        o.x = v[0]; o.y = v[1]; o.z = v[2]; o.w = v[3];
        dst[f] = o;
    }
}

extern "C" void kernel_launch(void* const* d_in, const int* in_sizes, int n_in,
                              void* d_out, int out_size, void* d_ws, size_t ws_size,
                              hipStream_t stream)
{
    const float* in = (const float*)d_in[0];
    float* out = (float*)d_out;
    // out_size = 64*512*1369 = 44,859,392 ; rows = 32768 ; 32768/4 = 8192 blocks
    unsigned n_rows = (unsigned)(out_size / OUT_ROW);
    unsigned blocks = n_rows / ROWS_PB;
    HexaToParallelogram_kernel<<<blocks, BLOCK, 0, stream>>>(in, out);
}

// Round 4
// 266.348 us; speedup vs baseline: 1.0566x; 1.0566x over previous
//
#include <hip/hip_runtime.h>

// HexaToParallelogram: out[b,s,qi,ri] = (|q+r|<=18) ? hexa[b,s,idx(q,r)] : 0
// with q=qi-18, r=ri-18, idx from the sorted (q,r) enumeration (1027 pixels).
//
// Closed-form index (verified against the Python _build_lookup construction):
//   prefix(q<=0) = (55+q)(q+18)/2
//   prefix(q>=0) = 495 + 37q - q(q-1)/2
//   idx(q,r)     = prefix(q) + r - max(-18, -18-q)
//
// Direct global gather (round-1 structure — measured faster than LDS staging):
// one thread per output float4; per-thread index decode done ONCE via magic
// division, then advanced with a cheap carry chain across the 4 elements.
// Gather loads within a q-row run are contiguous (37-element runs), so lanes
// are ~coalesced; stores are float4 nontemporal (write-once, never re-read).

#define IN_STRIDE   1039
#define OUT_ROW     1369        // 37*37
#define GDIM        37
#define BLOCK       256

typedef float f32x4 __attribute__((ext_vector_type(4)));  // clang vector: OK for nontemporal builtin

__global__ __launch_bounds__(BLOCK) void HexaToParallelogram_kernel(
        const float* __restrict__ in, float* __restrict__ out, unsigned int n_elems)
{
    unsigned int t  = blockIdx.x * BLOCK + threadIdx.x;   // one float4 per thread
    unsigned int e0 = t * 4u;
    if (e0 >= n_elems) return;

    // Decode once: row = e0/1369, j = e0%1369, qi = j/37, ri = j%37
    unsigned int row = e0 / OUT_ROW;
    unsigned int j   = e0 - row * OUT_ROW;
    int qi = (int)(j / GDIM);
    int ri = (int)j - qi * GDIM;
    size_t base = (size_t)row * IN_STRIDE;

    float v[4];
#pragma unroll
    for (int k = 0; k < 4; ++k) {
        int q = qi - 18;
        int r = ri - 18;
        int s = q + r;
        float val = 0.0f;
        if (s >= -18 && s <= 18) {
            int idx;
            if (q <= 0) {
                idx = ((55 + q) * (q + 18)) / 2 + r + 18 + q;
            } else {
                idx = 495 + 37 * q - (q * (q - 1)) / 2 + r + 18;
            }
            val = in[base + idx];
        }
        v[k] = val;
        // advance (ri,qi,row) with carry — no divisions
        if (++ri == GDIM) {
            ri = 0;
            if (++qi == GDIM) { qi = 0; base += IN_STRIDE; }
        }
    }

    f32x4 o;
    o.x = v[0]; o.y = v[1]; o.z = v[2]; o.w = v[3];
    __builtin_nontemporal_store(o, reinterpret_cast<f32x4*>(out) + t);
}

extern "C" void kernel_launch(void* const* d_in, const int* in_sizes, int n_in,
                              void* d_out, int out_size, void* d_ws, size_t ws_size,
                              hipStream_t stream)
{
    const float* in = (const float*)d_in[0];
    float* out = (float*)d_out;
    unsigned int n = (unsigned int)out_size;          // 64*512*1369 = 44,859,392
    unsigned int n4 = n / 4u;                         // divisible by 4
    unsigned int blocks = (n4 + BLOCK - 1u) / BLOCK;  // 43,808
    HexaToParallelogram_kernel<<<blocks, BLOCK, 0, stream>>>(in, out, n);
}